// Round 6
// baseline (21119.545 us; speedup 1.0000x reference)
//
#include <hip/hip_runtime.h>
#include <hip/hip_bf16.h>
#include <stdint.h>
#include <stddef.h>

#define B_SZ   4096
#define U_SZ   1024
#define SEQ    5
#define TSTEPS 200
#define STEPS  204          // 5 warmup + 199 decode LSTM steps

typedef __bf16 bf16_t;
typedef __bf16 bf16x8 __attribute__((ext_vector_type(8)));
typedef float  f32x4  __attribute__((ext_vector_type(4)));

#define AS1 __attribute__((address_space(1)))
#define AS3 __attribute__((address_space(3)))

#define LOAD_LDS16(gp, lp) \
    __builtin_amdgcn_global_load_lds((const AS1 unsigned int*)(gp), \
                                     (AS3 unsigned int*)(lp), 16, 0, 0)

__device__ __forceinline__ float fsig(float x) {
    return 1.0f / (1.0f + __expf(-x));
}
__device__ __forceinline__ float ftanh(float x) {
    x = fminf(fmaxf(x, -15.0f), 15.0f);
    float e = __expf(2.0f * x);
    return (e - 1.0f) / (e + 1.0f);
}

// ---------------------------------------------------------------------------
// Pack R (1024 x 4096 fp32 row-major) into per-wave-fragment order so the
// GEMM loads B fragments as single fully-coalesced dwordx4 per wave:
//   Rp[ub][kb][s][lane][e] : ub<32, kb<16, s<16, lane<64, e<8 (bf16)
//   s = wc*8 + ni*2 + kh ; n = ni*1024 + ub*32 + wc*16 + (lane&15)
//   k = kb*64 + kh*32 + (lane>>4)*8 + e
// ---------------------------------------------------------------------------
__global__ void pack_R(const float* __restrict__ R, bf16_t* __restrict__ Rp) {
    int idx = blockIdx.x * 256 + threadIdx.x;   // 4,194,304 total
    int e    = idx & 7;
    int lane = (idx >> 3) & 63;
    int s    = (idx >> 9) & 15;
    int kb   = (idx >> 13) & 15;
    int ub   = idx >> 17;
    int wc = s >> 3;
    int ni = (s >> 1) & 3;
    int kh = s & 1;
    int n  = ni * 1024 + ub * 32 + wc * 16 + (lane & 15);
    int k  = kb * 64 + kh * 32 + (lane >> 4) * 8 + e;
    Rp[idx] = (bf16_t)R[(size_t)k * 4096 + n];
}

// ---------------------------------------------------------------------------
// One LSTM step. Grid (16,32): p = panels {2p,2p+1}, G = batch rows G*128..+128.
// A (h): double-buffered LDS (XOR-swizzled rows), 1 barrier/kb.
// B (R): direct global->VGPR, coalesced 1KB fragment loads from the L2-pinned
//        packed panels, register double-buffered one kb ahead.
// ---------------------------------------------------------------------------
__global__ __launch_bounds__(256, 2)
void lstm_step(const bf16_t* __restrict__ hin,
               bf16_t* __restrict__ hout,
               float* __restrict__ cst,
               const bf16_t* __restrict__ Rp,
               const float* __restrict__ Wx,     // (4096,)
               const float* __restrict__ bias,   // (4096,)
               const float* __restrict__ w1,     // (1024,)
               const float* __restrict__ b1,
               const float* __restrict__ w2,
               const float* __restrict__ b2,
               const float* __restrict__ inputs, // [4096,5]
               float* __restrict__ praw,         // 3*4096
               float* __restrict__ out,          // [4096,200]
               int t)
{
    __shared__ __align__(16) bf16_t lsA[2][128 * 64];    // 2 x 16 KB
    __shared__ float lsX[128];

    const int tid  = threadIdx.x;
    const int wave = tid >> 6;
    const int lane = tid & 63;
    const int p    = blockIdx.x;   // 0..15
    const int G    = blockIdx.y;   // 0..31
    const int l15  = lane & 15;
    const int quad = lane >> 4;
    const int rbase = (wave >> 1) * 64;
    const int wc    = wave & 1;

    float*       pr_acc  = praw + (size_t)(t % 3) * B_SZ;
    const float* pr_read = praw + (size_t)((t + 2) % 3) * B_SZ;
    float*       pr_zero = praw + (size_t)((t + 1) % 3) * B_SZ;

    // ---- prologue: x for my 128 rows (+ out write + praw-slot zero) ----
    if (tid < 128) {
        int row = G * 128 + tid;
        float x;
        if (t < SEQ) {
            x = inputs[row * SEQ + t];
        } else {
            float x1 = fmaxf(pr_read[row] + b1[0], 0.f);
            x = (t == SEQ) ? x1 : x1 * w2[0] + b2[0];
            if (p == 0) out[(size_t)row * TSTEPS + (t - SEQ)] = x;
        }
        lsX[tid] = x;
        if (p == 0) pr_zero[row] = 0.f;
    }

    f32x4 acc[2][4][4] = {};
    const bf16_t* Ap = hin + (size_t)G * 128 * U_SZ;
    // per-wave fragment base: panel T, slab kb, slot s=wc*8+ni*2+kh, +lane*8
    const bf16_t* Bf0 = Rp + (size_t)(2 * p) * 131072 + (wc * 8) * 512 + lane * 8;
    const bf16_t* Bf1 = Bf0 + 131072;

    // A staging: lane writes phys slot (lane&7) of row chunk*8+(lane>>3);
    // logical slot = (lane&7)^(lane>>3)  -> source k offset:
    const int a_kk = (((lane & 7) ^ (lane >> 3)) << 3);
    const int a_m  = lane >> 3;

    // ---- preload kb=0: A via DMA, B into regs ----
    #pragma unroll
    for (int i = 0; i < 4; ++i) {
        int chunk = wave * 4 + i;
        LOAD_LDS16(Ap + (size_t)(chunk * 8 + a_m) * U_SZ + a_kk,
                   &lsA[0][chunk * 512]);
    }
    bf16x8 bfr[2][2][2][4];   // [buf][kh][T][ni]
    #pragma unroll
    for (int kh = 0; kh < 2; ++kh)
        #pragma unroll
        for (int ni = 0; ni < 4; ++ni) {
            bfr[0][kh][0][ni] = *(const bf16x8*)(Bf0 + (ni * 2 + kh) * 512);
            bfr[0][kh][1][ni] = *(const bf16x8*)(Bf1 + (ni * 2 + kh) * 512);
        }
    __syncthreads();

    #pragma unroll 2
    for (int kb = 0; kb < 16; ++kb) {
        const int cur = kb & 1, nxt = cur ^ 1;

        // stage A for kb+1 into the other LDS buffer
        if (kb < 15) {
            #pragma unroll
            for (int i = 0; i < 4; ++i) {
                int chunk = wave * 4 + i;
                LOAD_LDS16(Ap + (size_t)(chunk * 8 + a_m) * U_SZ
                               + (kb + 1) * 64 + a_kk,
                           &lsA[nxt][chunk * 512]);
            }
        }

        // A fragments for kb from LDS (swizzled)
        bf16x8 af[2][4];
        #pragma unroll
        for (int kh = 0; kh < 2; ++kh) {
            int sw = (((kh * 4 + quad) ^ (lane & 7)) << 3);
            #pragma unroll
            for (int mi = 0; mi < 4; ++mi)
                af[kh][mi] = *(const bf16x8*)
                    &lsA[cur][(rbase + mi * 16 + l15) * 64 + sw];
        }

        // prefetch B fragments for kb+1 (coalesced 1KB loads from L2)
        if (kb < 15) {
            const bf16_t* B0 = Bf0 + (size_t)(kb + 1) * 8192;
            const bf16_t* B1 = Bf1 + (size_t)(kb + 1) * 8192;
            #pragma unroll
            for (int kh = 0; kh < 2; ++kh)
                #pragma unroll
                for (int ni = 0; ni < 4; ++ni) {
                    bfr[nxt][kh][0][ni] = *(const bf16x8*)(B0 + (ni * 2 + kh) * 512);
                    bfr[nxt][kh][1][ni] = *(const bf16x8*)(B1 + (ni * 2 + kh) * 512);
                }
        }

        // 64 MFMAs for kb
        #pragma unroll
        for (int kh = 0; kh < 2; ++kh)
            #pragma unroll
            for (int T = 0; T < 2; ++T)
                #pragma unroll
                for (int mi = 0; mi < 4; ++mi)
                    #pragma unroll
                    for (int ni = 0; ni < 4; ++ni)
                        acc[T][mi][ni] = __builtin_amdgcn_mfma_f32_16x16x32_bf16(
                            af[kh][mi], bfr[cur][kh][T][ni], acc[T][mi][ni],
                            0, 0, 0);

        __syncthreads();   // A-DMA for nxt complete; buffers swap
    }

    // ---- epilogue: gates, c RMW (global fp32), h write, pred partials ----
    int uu[2];
    uu[0] = (2 * p) * 32 + wc * 16 + l15;
    uu[1] = uu[0] + 32;
    float g_b[2][4], g_w[2][4], w1u[2];
    #pragma unroll
    for (int T = 0; T < 2; ++T) {
        #pragma unroll
        for (int g = 0; g < 4; ++g) {
            g_b[T][g] = bias[g * 1024 + uu[T]];
            g_w[T][g] = Wx[g * 1024 + uu[T]];
        }
        w1u[T] = w1[uu[T]];
    }
    const bool do_pred = (t >= SEQ - 1);

    #pragma unroll
    for (int mi = 0; mi < 4; ++mi) {
        #pragma unroll
        for (int r = 0; r < 4; ++r) {
            int rl   = rbase + mi * 16 + quad * 4 + r;
            int brow = G * 128 + rl;
            float xv = lsX[rl];
            float ps = 0.f;
            #pragma unroll
            for (int T = 0; T < 2; ++T) {
                float zi = acc[T][mi][0][r] + g_b[T][0] + xv * g_w[T][0];
                float zf = acc[T][mi][1][r] + g_b[T][1] + xv * g_w[T][1];
                float zg = acc[T][mi][2][r] + g_b[T][2] + xv * g_w[T][2];
                float zo = acc[T][mi][3][r] + g_b[T][3] + xv * g_w[T][3];
                float ig = fsig(zi), fg = fsig(zf);
                float gg = ftanh(zg), og = fsig(zo);
                size_t off = (size_t)brow * U_SZ + uu[T];
                float cn = fg * cst[off] + ig * gg;
                cst[off] = cn;
                float hv = og * ftanh(cn);
                hout[off] = (bf16_t)hv;
                ps += hv * w1u[T];
            }
            if (do_pred) {
                ps += __shfl_xor(ps, 1);
                ps += __shfl_xor(ps, 2);
                ps += __shfl_xor(ps, 4);
                ps += __shfl_xor(ps, 8);
                if (l15 == 0) atomicAdd(&pr_acc[brow], ps);
            }
        }
    }
}

// final output slot 199 from praw of step 203 (203 % 3 == 2)
__global__ void pred_final(const float* __restrict__ praw,
                           const float* __restrict__ b1,
                           const float* __restrict__ w2,
                           const float* __restrict__ b2,
                           float* __restrict__ out)
{
    int row = blockIdx.x * 256 + threadIdx.x;
    float x1 = fmaxf(praw[2 * B_SZ + row] + b1[0], 0.f);
    out[(size_t)row * TSTEPS + 199] = x1 * w2[0] + b2[0];
}

extern "C" void kernel_launch(void* const* d_in, const int* in_sizes, int n_in,
                              void* d_out, int out_size, void* d_ws, size_t ws_size,
                              hipStream_t stream) {
    const float* inputs = (const float*)d_in[0];   // [4096,5,1]
    const float* Wx     = (const float*)d_in[1];   // [1,4096]
    const float* R      = (const float*)d_in[2];   // [1024,4096]
    const float* bias   = (const float*)d_in[3];   // [4096]
    const float* w1     = (const float*)d_in[4];   // [1024,1]
    const float* b1     = (const float*)d_in[5];
    const float* w2     = (const float*)d_in[6];
    const float* b2     = (const float*)d_in[7];
    float* out = (float*)d_out;

    char* ws = (char*)d_ws;
    const size_t RP_BYTES = (size_t)32 * 131072 * 2;          // 8 MB
    const size_t H_BYTES  = (size_t)B_SZ * U_SZ * 2;          // 8 MB
    const size_t C_BYTES  = (size_t)B_SZ * U_SZ * 4;          // 16 MB
    bf16_t* Rp   = (bf16_t*)ws;                ws += RP_BYTES;
    bf16_t* h0   = (bf16_t*)ws;                ws += H_BYTES;
    bf16_t* h1   = (bf16_t*)ws;                ws += H_BYTES;
    float*  cbuf = (float*)ws;                 ws += C_BYTES;
    float*  praw = (float*)ws;                 ws += 3 * B_SZ * 4;
    bf16_t* hb[2] = {h0, h1};

    hipMemsetAsync(h0, 0, H_BYTES, stream);
    hipMemsetAsync(cbuf, 0, C_BYTES, stream);
    hipMemsetAsync(praw, 0, 3 * B_SZ * 4, stream);

    pack_R<<<16384, 256, 0, stream>>>(R, Rp);

    dim3 grid(16, 32);   // p fastest -> B panels pinned per XCD
    int cur = 0;
    for (int t = 0; t < STEPS; ++t) {
        lstm_step<<<grid, 256, 0, stream>>>(hb[cur], hb[1 - cur], cbuf, Rp,
                                            Wx, bias, w1, b1, w2, b2,
                                            inputs, praw, out, t);
        cur ^= 1;
    }
    pred_final<<<16, 256, 0, stream>>>(praw, b1, w2, b2, out);
}

// Round 7
// 13118.561 us; speedup vs baseline: 1.6099x; 1.6099x over previous
//
#include <hip/hip_runtime.h>
#include <hip/hip_bf16.h>
#include <stdint.h>
#include <stddef.h>

#define B_SZ   4096
#define U_SZ   1024
#define SEQ    5
#define TSTEPS 200
#define STEPS  204          // 5 warmup + 199 decode LSTM steps

typedef __bf16 bf16_t;
typedef __bf16 bf16x8 __attribute__((ext_vector_type(8)));
typedef float  f32x4  __attribute__((ext_vector_type(4)));

#define AS1 __attribute__((address_space(1)))
#define AS3 __attribute__((address_space(3)))

#define LOAD_LDS16(gp, lp) \
    __builtin_amdgcn_global_load_lds((const AS1 unsigned int*)(gp), \
                                     (AS3 unsigned int*)(lp), 16, 0, 0)

__device__ __forceinline__ float fsig(float x) {
    return 1.0f / (1.0f + __expf(-x));
}
__device__ __forceinline__ float ftanh(float x) {
    x = fminf(fmaxf(x, -15.0f), 15.0f);
    float e = __expf(2.0f * x);
    return (e - 1.0f) / (e + 1.0f);
}

// ---------------------------------------------------------------------------
// Pack R (1024 x 4096 fp32 row-major) into per-wave-fragment order so the
// GEMM loads B fragments as single fully-coalesced dwordx4 per wave:
//   Rp[ub][kb][s][lane][e] : ub<32, kb<16, s<16, lane<64, e<8 (bf16)
//   s = wc*8 + ni*2 + kh ; n = ni*1024 + ub*32 + wc*16 + (lane&15)
//   k = kb*64 + kh*32 + (lane>>4)*8 + e
// ---------------------------------------------------------------------------
__global__ void pack_R(const float* __restrict__ R, bf16_t* __restrict__ Rp) {
    int idx = blockIdx.x * 256 + threadIdx.x;   // 4,194,304 total
    int e    = idx & 7;
    int lane = (idx >> 3) & 63;
    int s    = (idx >> 9) & 15;
    int kb   = (idx >> 13) & 15;
    int ub   = idx >> 17;
    int wc = s >> 3;
    int ni = (s >> 1) & 3;
    int kh = s & 1;
    int n  = ni * 1024 + ub * 32 + wc * 16 + (lane & 15);
    int k  = kb * 64 + kh * 32 + (lane >> 4) * 8 + e;
    Rp[idx] = (bf16_t)R[(size_t)k * 4096 + n];
}

// ---------------------------------------------------------------------------
// One LSTM step. Grid (16,32): p = panels {2p,2p+1}, G = batch rows G*128..+128.
// A (h): double-buffered LDS (XOR-swizzled rows), 1 barrier/kb.
// B (R): direct global->VGPR coalesced 1KB fragment loads, SINGLE register
//        buffer; kb+1's loads are issued right after the MFMAs that last read
//        those regs, and drain at the end-of-iter barrier (alongside A-DMA).
// ---------------------------------------------------------------------------
__global__ __launch_bounds__(256, 2)
void lstm_step(const bf16_t* __restrict__ hin,
               bf16_t* __restrict__ hout,
               float* __restrict__ cst,
               const bf16_t* __restrict__ Rp,
               const float* __restrict__ Wx,     // (4096,)
               const float* __restrict__ bias,   // (4096,)
               const float* __restrict__ w1,     // (1024,)
               const float* __restrict__ b1,
               const float* __restrict__ w2,
               const float* __restrict__ b2,
               const float* __restrict__ inputs, // [4096,5]
               float* __restrict__ praw,         // 3*4096
               float* __restrict__ out,          // [4096,200]
               int t)
{
    __shared__ __align__(16) bf16_t lsA[2][128 * 64];    // 2 x 16 KB
    __shared__ float lsX[128];

    const int tid  = threadIdx.x;
    const int wave = tid >> 6;
    const int lane = tid & 63;
    const int p    = blockIdx.x;   // 0..15
    const int G    = blockIdx.y;   // 0..31
    const int l15  = lane & 15;
    const int quad = lane >> 4;
    const int rbase = (wave >> 1) * 64;
    const int wc    = wave & 1;

    float*       pr_acc  = praw + (size_t)(t % 3) * B_SZ;
    const float* pr_read = praw + (size_t)((t + 2) % 3) * B_SZ;
    float*       pr_zero = praw + (size_t)((t + 1) % 3) * B_SZ;

    // ---- prologue: x for my 128 rows (+ out write + praw-slot zero) ----
    if (tid < 128) {
        int row = G * 128 + tid;
        float x;
        if (t < SEQ) {
            x = inputs[row * SEQ + t];
        } else {
            float x1 = fmaxf(pr_read[row] + b1[0], 0.f);
            x = (t == SEQ) ? x1 : x1 * w2[0] + b2[0];
            if (p == 0) out[(size_t)row * TSTEPS + (t - SEQ)] = x;
        }
        lsX[tid] = x;
        if (p == 0) pr_zero[row] = 0.f;
    }

    f32x4 acc[2][4][4] = {};
    const bf16_t* Ap = hin + (size_t)G * 128 * U_SZ;
    // per-wave fragment base: panel T, slab kb, slot s=wc*8+ni*2+kh, +lane*8
    const bf16_t* Bf0 = Rp + (size_t)(2 * p) * 131072 + (wc * 8) * 512 + lane * 8;
    const bf16_t* Bf1 = Bf0 + 131072;

    // A staging: lane writes phys slot (lane&7) of row chunk*8+(lane>>3);
    // logical slot = (lane&7)^(lane>>3)  -> source k offset:
    const int a_kk = (((lane & 7) ^ (lane >> 3)) << 3);
    const int a_m  = lane >> 3;

    // ---- preload kb=0: A via DMA, B into regs (single buffer) ----
    #pragma unroll
    for (int i = 0; i < 4; ++i) {
        int chunk = wave * 4 + i;
        LOAD_LDS16(Ap + (size_t)(chunk * 8 + a_m) * U_SZ + a_kk,
                   &lsA[0][chunk * 512]);
    }
    bf16x8 bfr[2][2][4];   // [kh][T][ni]
    #pragma unroll
    for (int kh = 0; kh < 2; ++kh)
        #pragma unroll
        for (int ni = 0; ni < 4; ++ni) {
            bfr[kh][0][ni] = *(const bf16x8*)(Bf0 + (ni * 2 + kh) * 512);
            bfr[kh][1][ni] = *(const bf16x8*)(Bf1 + (ni * 2 + kh) * 512);
        }
    __syncthreads();

    #pragma unroll 2
    for (int kb = 0; kb < 16; ++kb) {
        const int cur = kb & 1, nxt = cur ^ 1;
        const bf16_t* lsAc = lsA[cur];
        const bf16_t* Bn0 = Bf0 + (size_t)(kb + 1) * 8192;
        const bf16_t* Bn1 = Bf1 + (size_t)(kb + 1) * 8192;

        // stage A for kb+1 into the other LDS buffer
        if (kb < 15) {
            #pragma unroll
            for (int i = 0; i < 4; ++i) {
                int chunk = wave * 4 + i;
                LOAD_LDS16(Ap + (size_t)(chunk * 8 + a_m) * U_SZ
                               + (kb + 1) * 64 + a_kk,
                           &lsA[nxt][chunk * 512]);
            }
        }

        bf16x8 af[4];

        // ---- kh = 0 ----
        {
            int sw = ((quad ^ (lane & 7)) << 3);
            #pragma unroll
            for (int mi = 0; mi < 4; ++mi)
                af[mi] = *(const bf16x8*)
                    &lsAc[(rbase + mi * 16 + l15) * 64 + sw];
        }
        #pragma unroll
        for (int T = 0; T < 2; ++T)
            #pragma unroll
            for (int mi = 0; mi < 4; ++mi)
                #pragma unroll
                for (int ni = 0; ni < 4; ++ni)
                    acc[T][mi][ni] = __builtin_amdgcn_mfma_f32_16x16x32_bf16(
                        af[mi], bfr[0][T][ni], acc[T][mi][ni], 0, 0, 0);
        // bfr[0] fully consumed -> refill for kb+1 (drains at the barrier)
        if (kb < 15) {
            #pragma unroll
            for (int ni = 0; ni < 4; ++ni) {
                bfr[0][0][ni] = *(const bf16x8*)(Bn0 + (ni * 2) * 512);
                bfr[0][1][ni] = *(const bf16x8*)(Bn1 + (ni * 2) * 512);
            }
        }

        // ---- kh = 1 ----
        {
            int sw = (((4 + quad) ^ (lane & 7)) << 3);
            #pragma unroll
            for (int mi = 0; mi < 4; ++mi)
                af[mi] = *(const bf16x8*)
                    &lsAc[(rbase + mi * 16 + l15) * 64 + sw];
        }
        #pragma unroll
        for (int T = 0; T < 2; ++T)
            #pragma unroll
            for (int mi = 0; mi < 4; ++mi)
                #pragma unroll
                for (int ni = 0; ni < 4; ++ni)
                    acc[T][mi][ni] = __builtin_amdgcn_mfma_f32_16x16x32_bf16(
                        af[mi], bfr[1][T][ni], acc[T][mi][ni], 0, 0, 0);
        // bfr[1] consumed -> refill for kb+1
        if (kb < 15) {
            #pragma unroll
            for (int ni = 0; ni < 4; ++ni) {
                bfr[1][0][ni] = *(const bf16x8*)(Bn0 + (ni * 2 + 1) * 512);
                bfr[1][1][ni] = *(const bf16x8*)(Bn1 + (ni * 2 + 1) * 512);
            }
        }

        __syncthreads();   // drains A-DMA + B loads; buffers swap
    }

    // ---- epilogue: gates, c RMW (global fp32), h write, pred partials ----
    int uu[2];
    uu[0] = (2 * p) * 32 + wc * 16 + l15;
    uu[1] = uu[0] + 32;
    float g_b[2][4], g_w[2][4], w1u[2];
    #pragma unroll
    for (int T = 0; T < 2; ++T) {
        #pragma unroll
        for (int g = 0; g < 4; ++g) {
            g_b[T][g] = bias[g * 1024 + uu[T]];
            g_w[T][g] = Wx[g * 1024 + uu[T]];
        }
        w1u[T] = w1[uu[T]];
    }
    const bool do_pred = (t >= SEQ - 1);

    #pragma unroll
    for (int mi = 0; mi < 4; ++mi) {
        #pragma unroll
        for (int r = 0; r < 4; ++r) {
            int rl   = rbase + mi * 16 + quad * 4 + r;
            int brow = G * 128 + rl;
            float xv = lsX[rl];
            float ps = 0.f;
            #pragma unroll
            for (int T = 0; T < 2; ++T) {
                float zi = acc[T][mi][0][r] + g_b[T][0] + xv * g_w[T][0];
                float zf = acc[T][mi][1][r] + g_b[T][1] + xv * g_w[T][1];
                float zg = acc[T][mi][2][r] + g_b[T][2] + xv * g_w[T][2];
                float zo = acc[T][mi][3][r] + g_b[T][3] + xv * g_w[T][3];
                float ig = fsig(zi), fg = fsig(zf);
                float gg = ftanh(zg), og = fsig(zo);
                size_t off = (size_t)brow * U_SZ + uu[T];
                float cn = fg * cst[off] + ig * gg;
                cst[off] = cn;
                float hv = og * ftanh(cn);
                hout[off] = (bf16_t)hv;
                ps += hv * w1u[T];
            }
            if (do_pred) {
                ps += __shfl_xor(ps, 1);
                ps += __shfl_xor(ps, 2);
                ps += __shfl_xor(ps, 4);
                ps += __shfl_xor(ps, 8);
                if (l15 == 0) atomicAdd(&pr_acc[brow], ps);
            }
        }
    }
}

// final output slot 199 from praw of step 203 (203 % 3 == 2)
__global__ void pred_final(const float* __restrict__ praw,
                           const float* __restrict__ b1,
                           const float* __restrict__ w2,
                           const float* __restrict__ b2,
                           float* __restrict__ out)
{
    int row = blockIdx.x * 256 + threadIdx.x;
    float x1 = fmaxf(praw[2 * B_SZ + row] + b1[0], 0.f);
    out[(size_t)row * TSTEPS + 199] = x1 * w2[0] + b2[0];
}

extern "C" void kernel_launch(void* const* d_in, const int* in_sizes, int n_in,
                              void* d_out, int out_size, void* d_ws, size_t ws_size,
                              hipStream_t stream) {
    const float* inputs = (const float*)d_in[0];   // [4096,5,1]
    const float* Wx     = (const float*)d_in[1];   // [1,4096]
    const float* R      = (const float*)d_in[2];   // [1024,4096]
    const float* bias   = (const float*)d_in[3];   // [4096]
    const float* w1     = (const float*)d_in[4];   // [1024,1]
    const float* b1     = (const float*)d_in[5];
    const float* w2     = (const float*)d_in[6];
    const float* b2     = (const float*)d_in[7];
    float* out = (float*)d_out;

    char* ws = (char*)d_ws;
    const size_t RP_BYTES = (size_t)32 * 131072 * 2;          // 8 MB
    const size_t H_BYTES  = (size_t)B_SZ * U_SZ * 2;          // 8 MB
    const size_t C_BYTES  = (size_t)B_SZ * U_SZ * 4;          // 16 MB
    bf16_t* Rp   = (bf16_t*)ws;                ws += RP_BYTES;
    bf16_t* h0   = (bf16_t*)ws;                ws += H_BYTES;
    bf16_t* h1   = (bf16_t*)ws;                ws += H_BYTES;
    float*  cbuf = (float*)ws;                 ws += C_BYTES;
    float*  praw = (float*)ws;                 ws += 3 * B_SZ * 4;
    bf16_t* hb[2] = {h0, h1};

    hipMemsetAsync(h0, 0, H_BYTES, stream);
    hipMemsetAsync(cbuf, 0, C_BYTES, stream);
    hipMemsetAsync(praw, 0, 3 * B_SZ * 4, stream);

    pack_R<<<16384, 256, 0, stream>>>(R, Rp);

    dim3 grid(16, 32);   // p fastest -> B panels pinned per XCD
    int cur = 0;
    for (int t = 0; t < STEPS; ++t) {
        lstm_step<<<grid, 256, 0, stream>>>(hb[cur], hb[1 - cur], cbuf, Rp,
                                            Wx, bias, w1, b1, w2, b2,
                                            inputs, praw, out, t);
        cur ^= 1;
    }
    pred_final<<<16, 256, 0, stream>>>(praw, b1, w2, b2, out);
}

// Round 8
// 10811.797 us; speedup vs baseline: 1.9534x; 1.2134x over previous
//
#include <hip/hip_runtime.h>
#include <hip/hip_bf16.h>
#include <stdint.h>
#include <stddef.h>

#define B_SZ   4096
#define U_SZ   1024
#define SEQ    5
#define TSTEPS 200
#define STEPS  204          // 5 warmup + 199 decode LSTM steps

typedef __bf16 bf16_t;
typedef __bf16 bf16x8 __attribute__((ext_vector_type(8)));
typedef float  f32x4  __attribute__((ext_vector_type(4)));

#define AS1 __attribute__((address_space(1)))
#define AS3 __attribute__((address_space(3)))

#define LOAD_LDS16(gp, lp) \
    __builtin_amdgcn_global_load_lds((const AS1 unsigned int*)(gp), \
                                     (AS3 unsigned int*)(lp), 16, 0, 0)

__device__ __forceinline__ float fsig(float x) {
    return 1.0f / (1.0f + __expf(-x));
}
__device__ __forceinline__ float ftanh(float x) {
    x = fminf(fmaxf(x, -15.0f), 15.0f);
    float e = __expf(2.0f * x);
    return (e - 1.0f) / (e + 1.0f);
}

// ---------------------------------------------------------------------------
// Pack R (1024 x 4096 fp32 row-major) into per-wave-strip fragment order.
// A wave owns u-strip us (16 u's x 4 gates = 64 z-cols); its 8 fragments per
// kb are contiguous 1KB blocks ordered by lane:
//   Rp[us][kb][s][lane][e] : us<64, kb<16, s<8 (s=ni*2+kh), lane<64, e<8
//   n = ni*1024 + us*16 + (lane&15) ; k = kb*64 + kh*32 + (lane>>4)*8 + e
// ---------------------------------------------------------------------------
__global__ void pack_R(const float* __restrict__ R, bf16_t* __restrict__ Rp) {
    int idx = blockIdx.x * 256 + threadIdx.x;   // 4,194,304 total
    int e    = idx & 7;
    int lane = (idx >> 3) & 63;
    int s    = (idx >> 9) & 7;
    int kb   = (idx >> 12) & 15;
    int us   = idx >> 16;                       // 0..63
    int ni = s >> 1;
    int kh = s & 1;
    int n  = ni * 1024 + us * 16 + (lane & 15);
    int k  = kb * 64 + kh * 32 + (lane >> 4) * 8 + e;
    Rp[idx] = (bf16_t)R[(size_t)k * 4096 + n];
}

// ---------------------------------------------------------------------------
// One LSTM step. Grid (16,32): block p covers u-strips 4p..4p+3 (wave w owns
// strip 4p+w: all 128 rows x 64 cols), G = batch rows G*128..+128.
// A (h): double-buffered LDS (XOR-swizzled rows), shared by all 4 waves.
// B (R): direct global->VGPR coalesced 1KB loads, per-wave strips (no
//        duplication), single register buffer refilled right after last use.
// ---------------------------------------------------------------------------
__global__ __launch_bounds__(256, 2)
void lstm_step(const bf16_t* __restrict__ hin,
               bf16_t* __restrict__ hout,
               float* __restrict__ cst,
               const bf16_t* __restrict__ Rp,
               const float* __restrict__ Wx,     // (4096,)
               const float* __restrict__ bias,   // (4096,)
               const float* __restrict__ w1,     // (1024,)
               const float* __restrict__ b1,
               const float* __restrict__ w2,
               const float* __restrict__ b2,
               const float* __restrict__ inputs, // [4096,5]
               float* __restrict__ praw,         // 3*4096
               float* __restrict__ out,          // [4096,200]
               int t)
{
    __shared__ __align__(16) bf16_t lsA[2][128 * 64];    // 2 x 16 KB
    __shared__ float lsX[128];

    const int tid  = threadIdx.x;
    const int wave = tid >> 6;
    const int lane = tid & 63;
    const int p    = blockIdx.x;   // 0..15
    const int G    = blockIdx.y;   // 0..31
    const int l15  = lane & 15;
    const int quad = lane >> 4;

    float*       pr_acc  = praw + (size_t)(t % 3) * B_SZ;
    const float* pr_read = praw + (size_t)((t + 2) % 3) * B_SZ;
    float*       pr_zero = praw + (size_t)((t + 1) % 3) * B_SZ;

    // ---- prologue: x for my 128 rows (+ out write + praw-slot zero) ----
    if (tid < 128) {
        int row = G * 128 + tid;
        float x;
        if (t < SEQ) {
            x = inputs[row * SEQ + t];
        } else {
            float x1 = fmaxf(pr_read[row] + b1[0], 0.f);
            x = (t == SEQ) ? x1 : x1 * w2[0] + b2[0];
            if (p == 0) out[(size_t)row * TSTEPS + (t - SEQ)] = x;
        }
        lsX[tid] = x;
        if (p == 0) pr_zero[row] = 0.f;
    }

    f32x4 acc[8][4] = {};   // [mi][ni(=gate)]
    const bf16_t* Ap = hin + (size_t)G * 128 * U_SZ;
    const int us = 4 * p + wave;
    // wave-strip fragment base (+lane*8); slab kb: +kb*4096; slot: +(ni*2+kh)*512
    const bf16_t* Bf = Rp + (size_t)us * 65536 + lane * 8;

    // A staging: lane writes phys slot (lane&7) of row chunk*8+(lane>>3);
    // logical slot = (lane&7)^(lane>>3)  -> source k offset:
    const int a_kk = (((lane & 7) ^ (lane >> 3)) << 3);
    const int a_m  = lane >> 3;

    // ---- preload kb=0: A via DMA, B into regs (single buffer) ----
    #pragma unroll
    for (int i = 0; i < 4; ++i) {
        int chunk = wave * 4 + i;
        LOAD_LDS16(Ap + (size_t)(chunk * 8 + a_m) * U_SZ + a_kk,
                   &lsA[0][chunk * 512]);
    }
    bf16x8 bfr[2][4];   // [kh][ni]
    #pragma unroll
    for (int kh = 0; kh < 2; ++kh)
        #pragma unroll
        for (int ni = 0; ni < 4; ++ni)
            bfr[kh][ni] = *(const bf16x8*)(Bf + (ni * 2 + kh) * 512);
    __syncthreads();

    #pragma unroll 2
    for (int kb = 0; kb < 16; ++kb) {
        const int cur = kb & 1, nxt = cur ^ 1;
        const bf16_t* lsAc = lsA[cur];
        const bf16_t* Bn = Bf + (size_t)(kb + 1) * 4096;

        // stage A for kb+1 into the other LDS buffer
        if (kb < 15) {
            #pragma unroll
            for (int i = 0; i < 4; ++i) {
                int chunk = wave * 4 + i;
                LOAD_LDS16(Ap + (size_t)(chunk * 8 + a_m) * U_SZ
                               + (kb + 1) * 64 + a_kk,
                           &lsA[nxt][chunk * 512]);
            }
        }

        #pragma unroll
        for (int kh = 0; kh < 2; ++kh) {
            // A fragments: all 8 row-tiles (swizzled, conflict-free)
            bf16x8 af[8];
            int sw = (((kh * 4 + quad) ^ (l15 & 7)) << 3);
            #pragma unroll
            for (int mi = 0; mi < 8; ++mi)
                af[mi] = *(const bf16x8*)
                    &lsAc[(mi * 16 + l15) * 64 + sw];

            #pragma unroll
            for (int mi = 0; mi < 8; ++mi)
                #pragma unroll
                for (int ni = 0; ni < 4; ++ni)
                    acc[mi][ni] = __builtin_amdgcn_mfma_f32_16x16x32_bf16(
                        af[mi], bfr[kh][ni], acc[mi][ni], 0, 0, 0);

            // bfr[kh] fully consumed -> refill for kb+1 (drains at barrier)
            if (kb < 15) {
                #pragma unroll
                for (int ni = 0; ni < 4; ++ni)
                    bfr[kh][ni] = *(const bf16x8*)(Bn + (ni * 2 + kh) * 512);
            }
        }

        __syncthreads();   // drains A-DMA + B loads; buffers swap
    }

    // ---- epilogue: gates, c RMW (global fp32), h write, pred partials ----
    const int u = us * 16 + l15;    // one u per lane
    float g_b[4], g_w[4];
    #pragma unroll
    for (int g = 0; g < 4; ++g) {
        g_b[g] = bias[g * 1024 + u];
        g_w[g] = Wx[g * 1024 + u];
    }
    const float w1u = w1[u];
    const bool do_pred = (t >= SEQ - 1);

    #pragma unroll
    for (int mi = 0; mi < 8; ++mi) {
        #pragma unroll
        for (int r = 0; r < 4; ++r) {
            int rl   = mi * 16 + quad * 4 + r;
            int brow = G * 128 + rl;
            float xv = lsX[rl];
            float zi = acc[mi][0][r] + g_b[0] + xv * g_w[0];
            float zf = acc[mi][1][r] + g_b[1] + xv * g_w[1];
            float zg = acc[mi][2][r] + g_b[2] + xv * g_w[2];
            float zo = acc[mi][3][r] + g_b[3] + xv * g_w[3];
            float ig = fsig(zi), fg = fsig(zf);
            float gg = ftanh(zg), og = fsig(zo);
            size_t off = (size_t)brow * U_SZ + u;
            float cn = fg * cst[off] + ig * gg;
            cst[off] = cn;
            float hv = og * ftanh(cn);
            hout[off] = (bf16_t)hv;
            float ps = hv * w1u;
            if (do_pred) {
                ps += __shfl_xor(ps, 1);
                ps += __shfl_xor(ps, 2);
                ps += __shfl_xor(ps, 4);
                ps += __shfl_xor(ps, 8);
                if (l15 == 0) atomicAdd(&pr_acc[brow], ps);
            }
        }
    }
}

// final output slot 199 from praw of step 203 (203 % 3 == 2)
__global__ void pred_final(const float* __restrict__ praw,
                           const float* __restrict__ b1,
                           const float* __restrict__ w2,
                           const float* __restrict__ b2,
                           float* __restrict__ out)
{
    int row = blockIdx.x * 256 + threadIdx.x;
    float x1 = fmaxf(praw[2 * B_SZ + row] + b1[0], 0.f);
    out[(size_t)row * TSTEPS + 199] = x1 * w2[0] + b2[0];
}

extern "C" void kernel_launch(void* const* d_in, const int* in_sizes, int n_in,
                              void* d_out, int out_size, void* d_ws, size_t ws_size,
                              hipStream_t stream) {
    const float* inputs = (const float*)d_in[0];   // [4096,5,1]
    const float* Wx     = (const float*)d_in[1];   // [1,4096]
    const float* R      = (const float*)d_in[2];   // [1024,4096]
    const float* bias   = (const float*)d_in[3];   // [4096]
    const float* w1     = (const float*)d_in[4];   // [1024,1]
    const float* b1     = (const float*)d_in[5];
    const float* w2     = (const float*)d_in[6];
    const float* b2     = (const float*)d_in[7];
    float* out = (float*)d_out;

    char* ws = (char*)d_ws;
    const size_t RP_BYTES = (size_t)64 * 65536 * 2;           // 8 MB
    const size_t H_BYTES  = (size_t)B_SZ * U_SZ * 2;          // 8 MB
    const size_t C_BYTES  = (size_t)B_SZ * U_SZ * 4;          // 16 MB
    bf16_t* Rp   = (bf16_t*)ws;                ws += RP_BYTES;
    bf16_t* h0   = (bf16_t*)ws;                ws += H_BYTES;
    bf16_t* h1   = (bf16_t*)ws;                ws += H_BYTES;
    float*  cbuf = (float*)ws;                 ws += C_BYTES;
    float*  praw = (float*)ws;                 ws += 3 * B_SZ * 4;
    bf16_t* hb[2] = {h0, h1};

    hipMemsetAsync(h0, 0, H_BYTES, stream);
    hipMemsetAsync(cbuf, 0, C_BYTES, stream);
    hipMemsetAsync(praw, 0, 3 * B_SZ * 4, stream);

    pack_R<<<16384, 256, 0, stream>>>(R, Rp);

    dim3 grid(16, 32);   // p fastest -> B strips pinned per XCD
    int cur = 0;
    for (int t = 0; t < STEPS; ++t) {
        lstm_step<<<grid, 256, 0, stream>>>(hb[cur], hb[1 - cur], cbuf, Rp,
                                            Wx, bias, w1, b1, w2, b2,
                                            inputs, praw, out, t);
        cur ^= 1;
    }
    pred_final<<<16, 256, 0, stream>>>(praw, b1, w2, b2, out);
}